// Round 7
// baseline (683.301 us; speedup 1.0000x reference)
//
#include <hip/hip_runtime.h>
#include <hip/hip_bf16.h>
#include <stdint.h>

#define GN 8192
#define GF 128
#define NEG_SLOPE 0.2f
#define BIGM 700.0f       // exp(-700) == 0.0f: masked entries vanish exactly
#define PST 132           // P-tile LDS row stride (shorts)

typedef __attribute__((ext_vector_type(8))) short bf16x8;
typedef __attribute__((ext_vector_type(4))) float f32x4;

__device__ __forceinline__ unsigned fkey(float f) {
    unsigned u = __float_as_uint(f);
    return (u & 0x80000000u) ? ~u : (u | 0x80000000u);
}
__device__ __forceinline__ float funkey(unsigned k) {
    unsigned b = (k & 0x80000000u) ? (k & 0x7FFFFFFFu) : ~k;
    return __uint_as_float(b);
}
__device__ __forceinline__ unsigned short bf16rne(float f) {
    unsigned u = __float_as_uint(f);
    return (unsigned short)((u + 0x7FFFu + ((u >> 16) & 1u)) >> 16);
}
// pack two fp32 -> two bf16 (round-half-up) in one v_perm
__device__ __forceinline__ unsigned packbf(float lo, float hi) {
    return __builtin_amdgcn_perm(__float_as_uint(hi) + 0x8000u,
                                 __float_as_uint(lo) + 0x8000u, 0x07060302u);
}

// K1: x' = x@W + b (fp32); writes xpt in SWIZZLED MFMA-fragment order:
// elem(j, f) at [chunk=j/64][fg=f/16][half=(j%64)/32][q4=(j%32)/8][m16=f%16][jj=j%8]
// so a k2 B-frag load is one fully-coalesced 1KB transaction. Also s_src/s_dst.
__global__ __launch_bounds__(256) void gat_k1(
    const float* __restrict__ x, const float* __restrict__ w,
    const float* __restrict__ bias, const float* __restrict__ phi,
    unsigned short* __restrict__ xpt, float* __restrict__ s_src,
    float* __restrict__ s_dst)
{
    __shared__ float Xl[16][132];
    __shared__ float Wl[32][132];
    __shared__ unsigned short TR[128][24];
    const int tid = threadIdx.x;
    const int i0 = blockIdx.x * 16;

    #pragma unroll
    for (int q = 0; q < 2; q++) {                 // stage 16x128 x tile
        int flat = (q * 256 + tid) * 4;
        int r = flat >> 7, c = flat & 127;
        *(float4*)&Xl[r][c] = *(const float4*)&x[(size_t)(i0 + r) * GF + c];
    }

    const int rid = tid >> 5;          // 0..7 -> rows 2rid, 2rid+1
    const int c0  = (tid & 31) * 4;    // 4 consecutive features

    float acc[2][4] = {};
    for (int kc = 0; kc < 4; kc++) {   // W staged in 32-row chunks
        __syncthreads();
        #pragma unroll
        for (int q = 0; q < 4; q++) {
            int flat = (q * 256 + tid) * 4;
            int kk = flat >> 7, c = flat & 127;
            *(float4*)&Wl[kk][c] = *(const float4*)&w[(size_t)(kc * 32 + kk) * GF + c];
        }
        __syncthreads();
        #pragma unroll
        for (int k = 0; k < 32; k++) {
            float4 wv = *(const float4*)&Wl[k][c0];
            #pragma unroll
            for (int m = 0; m < 2; m++) {
                float xv = Xl[rid * 2 + m][kc * 32 + k];
                acc[m][0] = fmaf(xv, wv.x, acc[m][0]);
                acc[m][1] = fmaf(xv, wv.y, acc[m][1]);
                acc[m][2] = fmaf(xv, wv.z, acc[m][2]);
                acc[m][3] = fmaf(xv, wv.w, acc[m][3]);
            }
        }
    }

    float b4[4], p1[4], p2[4];
    #pragma unroll
    for (int q = 0; q < 4; q++) {
        b4[q] = bias[c0 + q];
        p1[q] = phi[c0 + q];
        p2[q] = phi[GF + c0 + q];
    }
    #pragma unroll
    for (int m = 0; m < 2; m++) {
        float ps = 0.f, pd = 0.f;
        #pragma unroll
        for (int q = 0; q < 4; q++) {
            float v = acc[m][q] + b4[q];
            ps = fmaf(v, p1[q], ps);
            pd = fmaf(v, p2[q], pd);
            TR[c0 + q][rid * 2 + m] = bf16rne(v);   // LDS transpose staging
        }
        #pragma unroll
        for (int s = 16; s >= 1; s >>= 1) {
            ps += __shfl_xor(ps, s, 64);
            pd += __shfl_xor(pd, s, 64);
        }
        if ((tid & 31) == 0) {
            s_src[i0 + rid * 2 + m] = ps;
            s_dst[i0 + rid * 2 + m] = pd;
        }
    }
    __syncthreads();
    {   // swizzled store: thread -> (feature f, node-octet oct), 16B each
        const int f = tid >> 1, oct = tid & 1;
        const int fg = f >> 4, mf = f & 15;
        const int chunk = i0 >> 6;
        const int half  = (i0 >> 5) & 1;
        const int q4b   = (((i0 & 31) >> 3)) + oct;   // {0,2}+oct
        const size_t base = (size_t)chunk * 8192 + fg * 1024 + half * 512
                          + q4b * 128 + mf * 8;
        *(uint4*)&xpt[base] = *(const uint4*)&TR[f][oct * 8];
    }
}

// K1b: D = max(s_dst). 8 blocks -> only 8 same-address atomics.
__global__ __launch_bounds__(256) void gat_k1b(
    const float* __restrict__ s_dst, unsigned* __restrict__ Dkey)
{
    __shared__ float sm[4];
    const int tid = threadIdx.x;
    const int idx = (blockIdx.x * 256 + tid) * 4;
    float4 v = *(const float4*)&s_dst[idx];
    float m = fmaxf(fmaxf(v.x, v.y), fmaxf(v.z, v.w));
    #pragma unroll
    for (int s = 32; s >= 1; s >>= 1) m = fmaxf(m, __shfl_xor(m, s, 64));
    if ((tid & 63) == 0) sm[tid >> 6] = m;
    __syncthreads();
    if (tid == 0) {
        m = fmaxf(fmaxf(sm[0], sm[1]), fmaxf(sm[2], sm[3]));
        atomicMax(Dkey, fkey(m));
    }
}

// K2: flash GAT, j-split 2-way for occupancy (grid 1024 -> 4 blocks/CU,
// 4 waves/SIMD). Block (ib, jh) does rows ib*16..+16 x cols jh*4096..+4096.
// B loads from swizzled xpt are single 1KB coalesced transactions.
// Partial O via fp32 atomicAdd into zeroed d_out; partial Z into zbuf.
__global__ __attribute__((amdgpu_waves_per_eu(4, 4)))
__launch_bounds__(256) void gat_k2(
    const float* __restrict__ adj, const unsigned short* __restrict__ xpt,
    const float* __restrict__ s_src, const float* __restrict__ s_dst,
    const unsigned* __restrict__ Dkey, float* __restrict__ outp,
    float* __restrict__ zbuf)
{
    __shared__ float smem[8448];     // loop: Pl tiles (first 16.9KB); epilogue: Ol[4][16][132]
    __shared__ float Zl[4][16];

    const int tid  = threadIdx.x;
    const int wave = tid >> 6, lane = tid & 63;
    const int m16  = lane & 15, q4 = lane >> 4;
    const int ib   = blockIdx.x >> 1, jh = blockIdx.x & 1;
    const int i0   = ib * 16;

    const float D = funkey(*Dkey);
    float si4[4], mneg4[4];          // per-lane softmax state for rows i0+4h+q4
    #pragma unroll
    for (int h = 0; h < 4; h++) {
        const float s = s_src[i0 + h * 4 + q4];
        si4[h] = s;
        const float t0 = s + D;
        mneg4[h] = -fmaxf(t0, NEG_SLOPE * t0);   // -Mi >= -(row max) bound
    }

    unsigned short* Plw = (unsigned short*)smem + wave * (16 * PST);
    const float* adjb = adj + (size_t)(i0 + q4) * GN + m16 * 4;
    const int cw = jh * 4096 + wave * 64;        // wave's first chunk col; +256/iter

    f32x4 acc[8];
    #pragma unroll
    for (int fg = 0; fg < 8; fg++) acc[fg] = (f32x4){0.f, 0.f, 0.f, 0.f};
    float z4[4] = {0.f, 0.f, 0.f, 0.f};

    float4 apfA[4], apfB[4];         // depth-2 ping-pong adj prefetch
    #pragma unroll
    for (int h = 0; h < 4; h++) {
        apfA[h] = *(const float4*)(adjb + (size_t)h * 4 * GN + cw);
        apfB[h] = *(const float4*)(adjb + (size_t)h * 4 * GN + cw + 256);
    }

    auto body = [&](int t, float4* apf) {
        const int cbase = cw + t * 256;

        // s_dst slice (L1-hot 32KB array; 256B contiguous per wave)
        const float4 d4 = *(const float4*)&s_dst[cbase + m16 * 4];

        // B-frags: swizzled -> each load is 1KB fully coalesced
        bf16x8 B0[8], B1[8];
        const unsigned short* xb = xpt + (size_t)(cbase >> 6) * 8192 + lane * 8;
        #pragma unroll
        for (int fg = 0; fg < 8; fg++) {
            B0[fg] = *(const bf16x8*)(xb + fg * 1024);
            B1[fg] = *(const bf16x8*)(xb + fg * 1024 + 512);
        }

        // P tile from prefetched adj (regs) + d4
        #pragma unroll
        for (int h = 0; h < 4; h++) {            // row i0+4h+q4, cols m16*4..+3
            const float4 a = apf[h];
            const float si = si4[h], mneg = mneg4[h];
            const int irh = i0 + h * 4 + q4;
            float p[4];
            #pragma unroll
            for (int q = 0; q < 4; q++) {
                const float tt = si + (&d4.x)[q];
                const float lr = fmaxf(tt, NEG_SLOPE * tt);
                float zz = fmaf((&a.x)[q], BIGM, lr + (mneg - BIGM));
                if (cbase + m16 * 4 + q == irh) zz = lr + mneg;  // self-loop
                p[q] = __expf(zz);
            }
            z4[h] += (p[0] + p[1]) + (p[2] + p[3]);
            *(uint2*)&Plw[(h * 4 + q4) * PST + m16 * 4] =
                make_uint2(packbf(p[0], p[1]), packbf(p[2], p[3]));
        }

        // A-frags from own-wave LDS tile (lgkmcnt only, no barrier)
        const bf16x8 af0 = *(const bf16x8*)&Plw[m16 * PST + q4 * 8];
        const bf16x8 af1 = *(const bf16x8*)&Plw[m16 * PST + 32 + q4 * 8];

        // adj prefetch for iter t+2 (youngest in vmcnt queue)
        if (t < 14) {
            #pragma unroll
            for (int h = 0; h < 4; h++)
                apf[h] = *(const float4*)(adjb + (size_t)h * 4 * GN + cbase + 512);
        }

        #pragma unroll
        for (int fg = 0; fg < 8; fg++)
            acc[fg] = __builtin_amdgcn_mfma_f32_16x16x32_bf16(af0, B0[fg], acc[fg], 0, 0, 0);
        #pragma unroll
        for (int fg = 0; fg < 8; fg++)
            acc[fg] = __builtin_amdgcn_mfma_f32_16x16x32_bf16(af1, B1[fg], acc[fg], 0, 0, 0);
    };

    #pragma unroll 1
    for (int t = 0; t < 16; t += 2) {
        body(t, apfA);
        body(t + 1, apfB);
    }

    // Z: reduce z4 across the 16 m16-lanes (same q4 => same row set)
    #pragma unroll
    for (int s = 1; s <= 8; s <<= 1)
        #pragma unroll
        for (int h = 0; h < 4; h++) z4[h] += __shfl_xor(z4[h], s, 64);

    __syncthreads();                 // all waves done with Plw; reuse smem as Ol
    #pragma unroll
    for (int fg = 0; fg < 8; fg++)   // C layout: col=lane&15, row=q4*4+v
        #pragma unroll
        for (int v = 0; v < 4; v++)
            smem[(wave * 16 + q4 * 4 + v) * 132 + fg * 16 + m16] = acc[fg][v];

    if (m16 == 0) {
        #pragma unroll
        for (int h = 0; h < 4; h++) Zl[wave][h * 4 + q4] = z4[h];
    }
    __syncthreads();

    {   // cross-wave reduce + atomic accumulate: thread -> row tid>>4, 8 cols
        const int r = tid >> 4, c = (tid & 15) * 8;
        float s[8];
        #pragma unroll
        for (int k = 0; k < 8; k++) s[k] = 0.f;
        #pragma unroll
        for (int wv = 0; wv < 4; wv++)
            #pragma unroll
            for (int k = 0; k < 8; k++)
                s[k] += smem[(wv * 16 + r) * 132 + c + k];
        #pragma unroll
        for (int k = 0; k < 8; k++)
            atomicAdd(&outp[(size_t)(i0 + r) * GF + c + k], s[k]);
        if (tid < 16) {
            const float zr = Zl[0][tid] + Zl[1][tid] + Zl[2][tid] + Zl[3][tid];
            atomicAdd(&zbuf[i0 + tid], zr);
        }
    }
}

// K3: out /= Z (row-wise), vectorized
__global__ __launch_bounds__(256) void gat_k3(
    float* __restrict__ outp, const float* __restrict__ zbuf)
{
    const int idx4 = blockIdx.x * 256 + threadIdx.x;
    const int row = idx4 >> 5;                  // 32 float4 per 128-f row
    f32x4 v = *(f32x4*)&outp[(size_t)idx4 * 4];
    v *= (1.0f / zbuf[row]);
    *(f32x4*)&outp[(size_t)idx4 * 4] = v;
}

extern "C" void kernel_launch(void* const* d_in, const int* in_sizes, int n_in,
                              void* d_out, int out_size, void* d_ws, size_t ws_size,
                              hipStream_t stream)
{
    (void)in_sizes; (void)n_in; (void)out_size; (void)ws_size;
    const float* adj  = (const float*)d_in[0];
    const float* x    = (const float*)d_in[1];
    const float* w    = (const float*)d_in[2];
    const float* bias = (const float*)d_in[3];
    const float* phi  = (const float*)d_in[4];
    float* out = (float*)d_out;

    char* ws = (char*)d_ws;
    unsigned short* xpt = (unsigned short*)ws;             // 2 MB bf16 x' swizzled
    float* s_src = (float*)(ws + (size_t)GF * GN * 2);     // 32 KB
    float* s_dst = s_src + GN;                             // 32 KB
    float* zbuf  = s_dst + GN;                             // 32 KB
    unsigned* Dkey = (unsigned*)(zbuf + GN);               // 4 B

    hipMemsetAsync(Dkey, 0, sizeof(unsigned), stream);
    hipMemsetAsync(zbuf, 0, GN * sizeof(float), stream);
    hipMemsetAsync(out, 0, (size_t)GN * GF * sizeof(float), stream);
    gat_k1 <<<GN / 16, 256, 0, stream>>>(x, w, bias, phi, xpt, s_src, s_dst);
    gat_k1b<<<8, 256, 0, stream>>>(s_dst, Dkey);
    gat_k2 <<<GN / 16 * 2, 256, 0, stream>>>(adj, xpt, s_src, s_dst, Dkey, out, zbuf);
    gat_k3 <<<GN * GF / 4 / 256, 256, 0, stream>>>(out, zbuf);
}

// Round 8
// 416.757 us; speedup vs baseline: 1.6396x; 1.6396x over previous
//
#include <hip/hip_runtime.h>
#include <hip/hip_bf16.h>
#include <stdint.h>

#define GN 8192
#define GF 128
#define NEG_SLOPE 0.2f
#define BIGM 700.0f       // exp(-700) == 0.0f: masked entries vanish exactly

typedef __attribute__((ext_vector_type(8))) short bf16x8;
typedef __attribute__((ext_vector_type(4))) float f32x4;

__device__ __forceinline__ unsigned fkey(float f) {
    unsigned u = __float_as_uint(f);
    return (u & 0x80000000u) ? ~u : (u | 0x80000000u);
}
__device__ __forceinline__ float funkey(unsigned k) {
    unsigned b = (k & 0x80000000u) ? (k & 0x7FFFFFFFu) : ~k;
    return __uint_as_float(b);
}
__device__ __forceinline__ unsigned short bf16rne(float f) {
    unsigned u = __float_as_uint(f);
    return (unsigned short)((u + 0x7FFFu + ((u >> 16) & 1u)) >> 16);
}
// pack two fp32 -> two bf16 (round-half-up) in one v_perm
__device__ __forceinline__ unsigned packbf(float lo, float hi) {
    return __builtin_amdgcn_perm(__float_as_uint(hi) + 0x8000u,
                                 __float_as_uint(lo) + 0x8000u, 0x07060302u);
}
// async global->LDS DMA, 16 B/lane: LDS dest = uniform base + lane*16
__device__ __forceinline__ void dma16(const unsigned short* g, unsigned short* l) {
    __builtin_amdgcn_global_load_lds(
        (const __attribute__((address_space(1))) unsigned int*)g,
        (__attribute__((address_space(3))) unsigned int*)l, 16, 0, 0);
}

// K1: x' = x@W + b (fp32); writes xpt in SWIZZLED MFMA-fragment order:
// elem(j, f) at [chunk=j/64][fg=f/16][half=(j%64)/32][q4=(j%32)/8][m16=f%16][jj=j%8]
// so a k2 B-slab DMA is a 1KB contiguous transfer in exact fragment order.
__global__ __launch_bounds__(256) void gat_k1(
    const float* __restrict__ x, const float* __restrict__ w,
    const float* __restrict__ bias, const float* __restrict__ phi,
    unsigned short* __restrict__ xpt, float* __restrict__ s_src,
    float* __restrict__ s_dst)
{
    __shared__ float Xl[16][132];
    __shared__ float Wl[32][132];
    __shared__ unsigned short TR[128][24];
    const int tid = threadIdx.x;
    const int i0 = blockIdx.x * 16;

    #pragma unroll
    for (int q = 0; q < 2; q++) {                 // stage 16x128 x tile
        int flat = (q * 256 + tid) * 4;
        int r = flat >> 7, c = flat & 127;
        *(float4*)&Xl[r][c] = *(const float4*)&x[(size_t)(i0 + r) * GF + c];
    }

    const int rid = tid >> 5;          // 0..7 -> rows 2rid, 2rid+1
    const int c0  = (tid & 31) * 4;    // 4 consecutive features

    float acc[2][4] = {};
    for (int kc = 0; kc < 4; kc++) {   // W staged in 32-row chunks
        __syncthreads();
        #pragma unroll
        for (int q = 0; q < 4; q++) {
            int flat = (q * 256 + tid) * 4;
            int kk = flat >> 7, c = flat & 127;
            *(float4*)&Wl[kk][c] = *(const float4*)&w[(size_t)(kc * 32 + kk) * GF + c];
        }
        __syncthreads();
        #pragma unroll
        for (int k = 0; k < 32; k++) {
            float4 wv = *(const float4*)&Wl[k][c0];
            #pragma unroll
            for (int m = 0; m < 2; m++) {
                float xv = Xl[rid * 2 + m][kc * 32 + k];
                acc[m][0] = fmaf(xv, wv.x, acc[m][0]);
                acc[m][1] = fmaf(xv, wv.y, acc[m][1]);
                acc[m][2] = fmaf(xv, wv.z, acc[m][2]);
                acc[m][3] = fmaf(xv, wv.w, acc[m][3]);
            }
        }
    }

    float b4[4], p1[4], p2[4];
    #pragma unroll
    for (int q = 0; q < 4; q++) {
        b4[q] = bias[c0 + q];
        p1[q] = phi[c0 + q];
        p2[q] = phi[GF + c0 + q];
    }
    #pragma unroll
    for (int m = 0; m < 2; m++) {
        float ps = 0.f, pd = 0.f;
        #pragma unroll
        for (int q = 0; q < 4; q++) {
            float v = acc[m][q] + b4[q];
            ps = fmaf(v, p1[q], ps);
            pd = fmaf(v, p2[q], pd);
            TR[c0 + q][rid * 2 + m] = bf16rne(v);   // LDS transpose staging
        }
        #pragma unroll
        for (int s = 16; s >= 1; s >>= 1) {
            ps += __shfl_xor(ps, s, 64);
            pd += __shfl_xor(pd, s, 64);
        }
        if ((tid & 31) == 0) {
            s_src[i0 + rid * 2 + m] = ps;
            s_dst[i0 + rid * 2 + m] = pd;
        }
    }
    __syncthreads();
    {   // swizzled store: thread -> (feature f, node-octet oct), 16B each
        const int f = tid >> 1, oct = tid & 1;
        const int fg = f >> 4, mf = f & 15;
        const int chunk = i0 >> 6;
        const int half  = (i0 >> 5) & 1;
        const int q4b   = (((i0 & 31) >> 3)) + oct;   // {0,2}+oct
        const size_t base = (size_t)chunk * 8192 + fg * 1024 + half * 512
                          + q4b * 128 + mf * 8;
        *(uint4*)&xpt[base] = *(const uint4*)&TR[f][oct * 8];
    }
}

// K1b: D = max(s_dst). 8 blocks -> only 8 same-address atomics.
__global__ __launch_bounds__(256) void gat_k1b(
    const float* __restrict__ s_dst, unsigned* __restrict__ Dkey)
{
    __shared__ float sm[4];
    const int tid = threadIdx.x;
    const int idx = (blockIdx.x * 256 + tid) * 4;
    float4 v = *(const float4*)&s_dst[idx];
    float m = fmaxf(fmaxf(v.x, v.y), fmaxf(v.z, v.w));
    #pragma unroll
    for (int s = 32; s >= 1; s >>= 1) m = fmaxf(m, __shfl_xor(m, s, 64));
    if ((tid & 63) == 0) sm[tid >> 6] = m;
    __syncthreads();
    if (tid == 0) {
        m = fmaxf(fmaxf(sm[0], sm[1]), fmaxf(sm[2], sm[3]));
        atomicMax(Dkey, fkey(m));
    }
}

// K2: barrier-free flash GAT with LDS-DMA B-staging.
// Block = 16 rows, 4 waves; wave w owns 32-col chunks in [w*2048,(w+1)*2048).
// Per iter: DMA next B-slab (8x1KB, zero VGPR) into the wave's OTHER private
// LDS buffer (BA/BB distinct objects -> per-object vmcnt tracking, no drain);
// adj + s_dst in depth-2 ping-pong regs; P tile in per-wave LDS; 8 MFMAs.
// No __syncthreads in the K-loop. Epilogue: 4-quarter cross-wave O reduce.
__global__ __launch_bounds__(256) void gat_k2(
    const float* __restrict__ adj, const unsigned short* __restrict__ xpt,
    const float* __restrict__ s_src, const float* __restrict__ s_dst,
    const unsigned* __restrict__ Dkey, float* __restrict__ out)
{
    __shared__ unsigned short BA[4][4096];   // 32 KB: per-wave B slab, buffer A
    __shared__ unsigned short BB[4][4096];   // 32 KB: buffer B
    __shared__ unsigned short Pt[4][640];    // per-wave P tile, row stride 40
    __shared__ float Zl[4][16];
    __shared__ float Ol[4][16][33];          // epilogue quarter-feature buffer

    const int tid  = threadIdx.x;
    const int wave = tid >> 6, lane = tid & 63;
    const int m16  = lane & 15, q4 = lane >> 4;
    const int r    = lane >> 2;        // P row this lane computes (0..15)
    const int c8   = (lane & 3) * 8;   // col octet within 32-col chunk
    const int i0   = blockIdx.x * 16;
    const int irow = i0 + r;

    const float D  = funkey(*Dkey);
    const float si = s_src[irow];
    const float t0 = si + D;
    const float mneg = -fmaxf(t0, NEG_SLOPE * t0);   // -Mi >= -(row max) bound
    const float base = mneg - BIGM;

    const float* arow = adj + (size_t)irow * GN + c8;
    unsigned short* Pw  = Pt[wave];
    unsigned short* BAw = BA[wave];
    unsigned short* BBw = BB[wave];
    const int cw = wave * 2048;        // wave's j-range start

    f32x4 acc[8];
    #pragma unroll
    for (int fg = 0; fg < 8; fg++) acc[fg] = (f32x4){0.f, 0.f, 0.f, 0.f};
    float z = 0.f;

    // ---- prologue: DMA chunk 0 -> BA; adj/s_dst regs for t=0 (A) and t=1 (B)
    {
        const unsigned short* src = xpt + (size_t)(cw >> 6) * 8192
                                  + (size_t)((cw >> 5) & 1) * 512 + lane * 8;
        #pragma unroll
        for (int fg = 0; fg < 8; fg++)
            dma16(src + fg * 1024, BAw + fg * 512);
    }
    float4 aA0 = *(const float4*)(arow + cw);
    float4 aA1 = *(const float4*)(arow + cw + 4);
    float4 dA0 = *(const float4*)(s_dst + cw + c8);
    float4 dA1 = *(const float4*)(s_dst + cw + c8 + 4);
    float4 aB0 = *(const float4*)(arow + cw + 32);
    float4 aB1 = *(const float4*)(arow + cw + 36);
    float4 dB0 = *(const float4*)(s_dst + cw + 32 + c8);
    float4 dB1 = *(const float4*)(s_dst + cw + 32 + c8 + 4);

    auto body = [&](int t, unsigned short* Brd, unsigned short* Bwr,
                    float4& pa0, float4& pa1, float4& pd0, float4& pd1) {
        const int cbase = cw + t * 32;
        const float4 a0 = pa0, a1 = pa1, d0 = pd0, d1 = pd1;

        if (t + 1 < 64) {   // DMA chunk t+1 into the other buffer (no VGPRs)
            const int nb = cbase + 32;
            const unsigned short* src = xpt + (size_t)(nb >> 6) * 8192
                                      + (size_t)((nb >> 5) & 1) * 512 + lane * 8;
            #pragma unroll
            for (int fg = 0; fg < 8; fg++)
                dma16(src + fg * 1024, Bwr + fg * 512);
        }
        if (t + 2 < 64) {   // adj + s_dst register prefetch for t+2
            const int pb = cbase + 64;
            pa0 = *(const float4*)(arow + pb);
            pa1 = *(const float4*)(arow + pb + 4);
            pd0 = *(const float4*)(s_dst + pb + c8);
            pd1 = *(const float4*)(s_dst + pb + c8 + 4);
        }

        // P: row irow, cols cbase+c8 .. +8
        float p[8];
        #pragma unroll
        for (int q = 0; q < 8; q++) {
            const float sd = (q < 4) ? (&d0.x)[q] : (&d1.x)[q - 4];
            const float aq = (q < 4) ? (&a0.x)[q] : (&a1.x)[q - 4];
            const float tt = si + sd;
            const float lr = fmaxf(tt, NEG_SLOPE * tt);
            float zz = fmaf(aq, BIGM, lr + base);
            if (cbase + c8 + q == irow) zz = lr + mneg;   // self-loop kept
            p[q] = __expf(zz);
            z += p[q];
        }
        uint4 pk;
        pk.x = packbf(p[0], p[1]); pk.y = packbf(p[2], p[3]);
        pk.z = packbf(p[4], p[5]); pk.w = packbf(p[6], p[7]);
        *(uint4*)&Pw[r * 40 + c8] = pk;          // 16B-aligned (stride 80B)

        // A-frag (own-wave LDS, lgkm only) + 8 B-frags from DMA'd slab
        const bf16x8 af = *(const bf16x8*)&Pw[m16 * 40 + q4 * 8];
        #pragma unroll
        for (int fg = 0; fg < 8; fg++) {
            const bf16x8 bf = *(const bf16x8*)&Brd[fg * 512 + lane * 8];
            acc[fg] = __builtin_amdgcn_mfma_f32_16x16x32_bf16(af, bf, acc[fg], 0, 0, 0);
        }
    };

    #pragma unroll 1
    for (int t = 0; t < 64; t += 2) {
        body(t,     BAw, BBw, aA0, aA1, dA0, dA1);
        body(t + 1, BBw, BAw, aB0, aB1, dB0, dB1);
    }

    // Z: lanes 4r..4r+3 hold row r partials for this wave
    z += __shfl_xor(z, 1, 64);
    z += __shfl_xor(z, 2, 64);
    if ((lane & 3) == 0) Zl[wave][r] = z;
    __syncthreads();

    const int er = tid >> 4;            // epilogue row 0..15
    const int ef = (tid & 15) * 2;      // feat pair within 32-feat quarter
    const float zinv = 1.0f / (Zl[0][er] + Zl[1][er] + Zl[2][er] + Zl[3][er]);

    #pragma unroll
    for (int qp = 0; qp < 4; qp++) {    // cross-wave O reduce, 32 feats/pass
        #pragma unroll
        for (int g = 0; g < 2; g++) {   // C layout: col=lane&15, row=q4*4+v
            const int fg = qp * 2 + g;
            #pragma unroll
            for (int v = 0; v < 4; v++)
                Ol[wave][q4 * 4 + v][g * 16 + m16] = acc[fg][v];
        }
        __syncthreads();
        float o0 = 0.f, o1 = 0.f;
        #pragma unroll
        for (int wv = 0; wv < 4; wv++) {
            o0 += Ol[wv][er][ef];
            o1 += Ol[wv][er][ef + 1];
        }
        *(float2*)&out[(size_t)(i0 + er) * GF + qp * 32 + ef] =
            make_float2(o0 * zinv, o1 * zinv);
        __syncthreads();
    }
}

extern "C" void kernel_launch(void* const* d_in, const int* in_sizes, int n_in,
                              void* d_out, int out_size, void* d_ws, size_t ws_size,
                              hipStream_t stream)
{
    (void)in_sizes; (void)n_in; (void)out_size; (void)ws_size;
    const float* adj  = (const float*)d_in[0];
    const float* x    = (const float*)d_in[1];
    const float* w    = (const float*)d_in[2];
    const float* bias = (const float*)d_in[3];
    const float* phi  = (const float*)d_in[4];
    float* out = (float*)d_out;

    char* ws = (char*)d_ws;
    unsigned short* xpt = (unsigned short*)ws;             // 2 MB bf16 x' swizzled
    float* s_src = (float*)(ws + (size_t)GF * GN * 2);     // 32 KB
    float* s_dst = s_src + GN;                             // 32 KB
    unsigned* Dkey = (unsigned*)(s_dst + GN);              // 4 B

    hipMemsetAsync(Dkey, 0, sizeof(unsigned), stream);
    gat_k1 <<<GN / 16, 256, 0, stream>>>(x, w, bias, phi, xpt, s_src, s_dst);
    gat_k1b<<<8, 256, 0, stream>>>(s_dst, Dkey);
    gat_k2 <<<GN / 16, 256, 0, stream>>>(adj, xpt, s_src, s_dst, Dkey, out);
}